// Round 8
// baseline (191.191 us; speedup 1.0000x reference)
//
#include <hip/hip_runtime.h>
#include <math.h>

#define SS 512
#define BB 512
#define TT 64
#define GRP 8

typedef float vf16 __attribute__((ext_vector_type(16)));
typedef float vf8  __attribute__((ext_vector_type(8)));
typedef int   vi8  __attribute__((ext_vector_type(8)));

__device__ __forceinline__ float bl0(float x) {
    return __int_as_float(__builtin_amdgcn_readfirstlane(__float_as_int(x)));
}

// Exact power-of-2 renormalization: scale state so lane0 lands in [1,2);
// accumulate the integer exponent in Lexp. All-scalar except one v_mul.
__device__ __forceinline__ float renorm(float sel, int& Lexp) {
    int bits = __float_as_int(bl0(sel)) & 0x7f800000;
    bits = bits < 0x00800000 ? 0x00800000 : bits;   // guard denormal/zero
    bits = bits > 0x7e800000 ? 0x7e800000 : bits;   // guard inf/huge
    Lexp += (bits >> 23) - 127;
    float scale = __int_as_float(0x7f000000 - bits); // 2^-(E-127), exact
    return sel * scale;
}

// Broadcast matvec via LDS uniform reads: state vector sits at pb (64 floats,
// 16B aligned); all 64 lanes read the SAME addresses (ds_read_b128 broadcast,
// conflict-free) -> operands arrive as VGPRs, zero readlane/SGPR traffic.
// E strided across 4 chains: eA[i]=e[4i], eB[i]=e[4i+1], eC[i]=e[4i+2], eD[i]=e[4i+3].
__device__ __forceinline__ float bcast_matvec(const float* pb,
                                              vf16 eA, vf16 eB, vf16 eC, vf16 eD) {
    const float4* pv = (const float4*)pb;
    float a0 = 0.f, a1 = 0.f, a2 = 0.f, a3 = 0.f;
    #pragma unroll
    for (int i = 0; i < 16; ++i) {
        float4 x = pv[i];              // uniform address -> broadcast
        a0 = fmaf(x.x, eA[i], a0);
        a1 = fmaf(x.y, eB[i], a1);
        a2 = fmaf(x.z, eC[i], a2);
        a3 = fmaf(x.w, eD[i], a3);
    }
    return (a0 + a1) + (a2 + a3);
}

#define LOADF(EV, MV, g) do {                                              \
    const int sb_ = 1 + (g) * GRP;                                         \
    _Pragma("unroll")                                                      \
    for (int k_ = 0; k_ < GRP; ++k_) {                                     \
        EV[k_] = embase[(size_t)(sb_ + k_) * BB * TT];                     \
        MV[k_] = mkbase[(sb_ + k_) * BB];                                  \
    } } while (0)

// step: p (renormalized, exp domain) lives in pb[par]; write new p to pb[1-par]
#define STEPSF(EV, MV, lastg) do {                                         \
    vf8 Em_;                                                               \
    _Pragma("unroll")                                                      \
    for (int k_ = 0; k_ < GRP; ++k_) Em_[k_] = __expf(EV[k_]);             \
    _Pragma("unroll")                                                      \
    for (int k_ = 0; k_ < GRP; ++k_) {                                     \
        const int par_ = k_ & 1;                                           \
        float acc_ = bcast_matvec(pb + par_ * TT, eA, eB, eC, eD);         \
        float t_   = acc_ * Em_[k_];                                       \
        int   mk_  = MV[k_];                                               \
        if (k_ == GRP - 1) mk_ = (lastg) ? 0 : mk_;  /* virtual step 256 */\
        float sel_ = mk_ ? t_ : p;                                         \
        p = renorm(sel_, Lexp);                                            \
        pb[(1 - par_) * TT + lane] = p;                                    \
    } } while (0)

#define LOADB(EV, MV, g) do {                                              \
    const int sb_ = 511 - (g) * GRP;                                       \
    _Pragma("unroll")                                                      \
    for (int k_ = 0; k_ < GRP; ++k_) {                                     \
        EV[k_] = embase[(size_t)(sb_ - k_) * BB * TT];                     \
        MV[k_] = mkbase[(sb_ - k_) * BB];                                  \
    } } while (0)

// bwd step: u_j = q_j * Em_j broadcast; beta'_i = sum_j E[i][j] u_j
#define STEPSB(EV, MV) do {                                                \
    vf8 Em_;                                                               \
    _Pragma("unroll")                                                      \
    for (int k_ = 0; k_ < GRP; ++k_) Em_[k_] = __expf(EV[k_]);             \
    _Pragma("unroll")                                                      \
    for (int k_ = 0; k_ < GRP; ++k_) {                                     \
        const int par_ = k_ & 1;                                           \
        float u_ = q * Em_[k_];                                            \
        pb[par_ * TT + lane] = u_;                                         \
        float acc_ = bcast_matvec(pb + par_ * TT, eA, eB, eC, eD);         \
        float sel_ = MV[k_] ? acc_ : q;                                    \
        q = renorm(sel_, Lexp);                                            \
    } } while (0)

// blocks [0,B): forward chains; [B,2B): backward chains; [2B,3B): numerator.
// One wave per block; no barriers in the recursion (single wave: DS ops are
// in-order per wave; parity ping-pong removes WAR hazards).
__global__ __launch_bounds__(64, 1) void crf_chains(
    const float* __restrict__ em,      // S,B,T
    const int*   __restrict__ tags,    // S,B
    const int*   __restrict__ mask,    // S,B
    const float* __restrict__ start_t, // T
    const float* __restrict__ end_t,   // T
    const float* __restrict__ trans,   // T,T
    float* __restrict__ alpha_mid,     // B,T
    float* __restrict__ beta_mid,      // B,T
    float* __restrict__ num_ws)        // B
{
    const int lane = threadIdx.x;
    const int bid  = blockIdx.x;
    __shared__ __align__(16) float pb[2 * TT];   // broadcast ping-pong
    __shared__ float lds[TT * 65];               // bwd transpose staging

    if (bid < BB) {
        // ------------- forward: alpha_0 .. alpha_255 (exp domain) -------------
        const int b = bid;
        const float* embase = em + (size_t)b * TT + lane;
        const int*   mkbase = mask + b;

        vf16 eA, eB, eC, eD;   // strided: eA[i]=exp(trans[4i][lane]) etc. (columns of E)
        #pragma unroll
        for (int i = 0; i < 16; ++i) {
            eA[i] = __expf(trans[(4 * i + 0) * TT + lane]);
            eB[i] = __expf(trans[(4 * i + 1) * TT + lane]);
            eC[i] = __expf(trans[(4 * i + 2) * TT + lane]);
            eD[i] = __expf(trans[(4 * i + 3) * TT + lane]);
        }

        float av    = start_t[lane] + embase[0];
        float Lbase = bl0(av);
        float p     = __expf(av - Lbase);
        int   Lexp  = 0;
        pb[lane] = p;                               // initial state in buffer 0

        vf8 em0, em1;
        vi8 mk0, mk1;

        LOADF(em0, mk0, 0);
        LOADF(em1, mk1, 1);
        for (int gg = 0; gg < 32; gg += 2) {
            STEPSF(em0, mk0, false);
            LOADF(em0, mk0, gg + 2);
            STEPSF(em1, mk1, gg + 1 == 31);
            LOADF(em1, mk1, gg + 3);
        }
        double a = (double)Lbase + (double)Lexp * 0.6931471805599453 + (double)__logf(p);
        alpha_mid[(size_t)b * TT + lane] = (float)a;

    } else if (bid < 2 * BB) {
        // ------------- backward: beta_511 .. beta_255 (exp domain) -------------
        const int b = bid - BB;
        const float* embase = em + (size_t)b * TT + lane;
        const int*   mkbase = mask + b;

        // row lane of E via LDS transpose (coalesced global, conflict-free LDS)
        for (int k = 0; k < TT; ++k)
            lds[k * 65 + lane] = trans[k * TT + lane];
        vf16 eA, eB, eC, eD;   // strided rows: eA[i]=exp(trans[lane][4i]) etc.
        #pragma unroll
        for (int j = 0; j < 16; ++j) {
            eA[j] = __expf(lds[lane * 65 + 4 * j + 0]);
            eB[j] = __expf(lds[lane * 65 + 4 * j + 1]);
            eC[j] = __expf(lds[lane * 65 + 4 * j + 2]);
            eD[j] = __expf(lds[lane * 65 + 4 * j + 3]);
        }

        float q    = __expf(end_t[lane]);
        int   Lexp = 0;

        vf8 em0, em1;
        vi8 mk0, mk1;

        LOADB(em0, mk0, 0);
        LOADB(em1, mk1, 1);
        for (int gg = 0; gg < 32; gg += 2) {
            STEPSB(em0, mk0);
            LOADB(em0, mk0, gg + 2);
            STEPSB(em1, mk1);
            LOADB(em1, mk1, gg + 3);
        }
        double bsum = (double)Lexp * 0.6931471805599453 + (double)__logf(q);
        beta_mid[(size_t)b * TT + lane] = (float)bsum;

    } else {
        // ---------------- numerator (tag-path score) ----------------
        const int b = bid - 2 * BB;
        float local = 0.f;
        int   mcnt  = 0;
        for (int s = lane; s < SS; s += 64) {
            int tag = tags[s * BB + b];
            int mk  = mask[s * BB + b];
            mcnt += mk;
            if (s == 0) {
                local += start_t[tag] + em[(size_t)b * TT + tag];
            } else if (mk) {
                int tp = tags[(s - 1) * BB + b];
                local += trans[tp * TT + tag] + em[(size_t)s * BB * TT + (size_t)b * TT + tag];
            }
        }
        #pragma unroll
        for (int d = 32; d > 0; d >>= 1) {
            local += __shfl_down(local, d, 64);
            mcnt  += __shfl_down(mcnt, d, 64);
        }
        if (lane == 0) {
            int last = tags[(mcnt - 1) * BB + b];
            num_ws[b] = local + end_t[last];
        }
    }
}

// per-batch denominator + llh: 64 blocks x 8 waves, one wave per batch.
__global__ __launch_bounds__(512) void crf_llh(
    const float* __restrict__ alpha_mid,
    const float* __restrict__ beta_mid,
    const float* __restrict__ num_ws,
    float* __restrict__ llh)
{
    const int lane = threadIdx.x & 63;
    const int b    = blockIdx.x * 8 + (threadIdx.x >> 6);
    float v = alpha_mid[(size_t)b * TT + lane] + beta_mid[(size_t)b * TT + lane];
    float mx = v;
    #pragma unroll
    for (int d = 32; d > 0; d >>= 1) mx = fmaxf(mx, __shfl_xor(mx, d, 64));
    float s = __expf(v - mx);
    #pragma unroll
    for (int d = 32; d > 0; d >>= 1) s += __shfl_xor(s, d, 64);
    if (lane == 0) llh[b] = num_ws[b] - (mx + __logf(s));
}

__global__ __launch_bounds__(512) void crf_mean(const float* __restrict__ llh,
                                               float* __restrict__ out)
{
    const int t = threadIdx.x;
    float v = llh[t];
    #pragma unroll
    for (int d = 32; d > 0; d >>= 1) v += __shfl_down(v, d, 64);
    __shared__ float red[8];
    if ((t & 63) == 0) red[t >> 6] = v;
    __syncthreads();
    if (t == 0) {
        float s = 0.f;
        #pragma unroll
        for (int w = 0; w < 8; ++w) s += red[w];
        out[0] = s / (float)BB;
    }
}

extern "C" void kernel_launch(void* const* d_in, const int* in_sizes, int n_in,
                              void* d_out, int out_size, void* d_ws, size_t ws_size,
                              hipStream_t stream) {
    const float* em    = (const float*)d_in[0];
    const int*   tags  = (const int*)d_in[1];
    const int*   mask  = (const int*)d_in[2];
    const float* st    = (const float*)d_in[3];
    const float* en    = (const float*)d_in[4];
    const float* tr    = (const float*)d_in[5];

    float* ws        = (float*)d_ws;
    float* alpha_mid = ws;
    float* beta_mid  = ws + (size_t)BB * TT;
    float* num_ws    = ws + (size_t)2 * BB * TT;
    float* llh       = ws + (size_t)2 * BB * TT + BB;

    crf_chains<<<3 * BB, 64, 0, stream>>>(em, tags, mask, st, en, tr,
                                          alpha_mid, beta_mid, num_ws);
    crf_llh<<<BB / 8, 512, 0, stream>>>(alpha_mid, beta_mid, num_ws, llh);
    crf_mean<<<1, 512, 0, stream>>>(llh, (float*)d_out);
}

// Round 9
// 167.466 us; speedup vs baseline: 1.1417x; 1.1417x over previous
//
#include <hip/hip_runtime.h>
#include <math.h>

#define SS 512
#define BB 512
#define TT 64
#define GRP 8

typedef float vf16 __attribute__((ext_vector_type(16)));
typedef float vf8  __attribute__((ext_vector_type(8)));
typedef int   vi8  __attribute__((ext_vector_type(8)));

__device__ __forceinline__ float bl0(float x) {
    return __int_as_float(__builtin_amdgcn_readfirstlane(__float_as_int(x)));
}

// Exact power-of-2 renormalization: scale state so lane0 lands in [1,2);
// accumulate the integer exponent in Lexp. All-scalar except one v_mul.
__device__ __forceinline__ float renorm(float sel, int& Lexp) {
    int bits = __float_as_int(bl0(sel)) & 0x7f800000;
    bits = bits < 0x00800000 ? 0x00800000 : bits;   // guard denormal/zero
    bits = bits > 0x7e800000 ? 0x7e800000 : bits;   // guard inf/huge
    Lexp += (bits >> 23) - 127;
    float scale = __int_as_float(0x7f000000 - bits); // 2^-(E-127), exact
    return sel * scale;
}

// Half-split swizzle matvec: res_j = sum_{i=0..63} x_i * E'[i][j].
// ds_swizzle (BitMode, and=0, or=i -> offset i<<5) broadcasts lane i within
// each 32-lane half: lanes<32 see x_i, lanes>=32 see x_{32+i}. Each lane
// accumulates its own half-sum c (E-layout e1) and its partner's missing
// half-sum d (E-layout e2); one shfl_xor(32) stitches: res = c + d_partner.
// All VGPR traffic, no SGPR writes, no bank access (pure crossbar).
__device__ __forceinline__ float swz_matvec(float x,
    const vf16& e1a, const vf16& e1b, const vf16& e2a, const vf16& e2b)
{
    const int xi = __float_as_int(x);
    float c0 = 0.f, c1 = 0.f, c2 = 0.f, c3 = 0.f;
    float d0 = 0.f, d1 = 0.f, d2 = 0.f, d3 = 0.f;
#define SWZFMA(I, CC, DD, EV1, EV2, K) do {                                   \
    float b_ = __int_as_float(__builtin_amdgcn_ds_swizzle(xi, (I) << 5));     \
    CC = fmaf(b_, EV1[K], CC);                                                \
    DD = fmaf(b_, EV2[K], DD); } while (0)
#define SWZ8(B, CC, DD, EV1, EV2, KB)                                          \
    SWZFMA(B + 0, CC, DD, EV1, EV2, KB + 0); SWZFMA(B + 1, CC, DD, EV1, EV2, KB + 1); \
    SWZFMA(B + 2, CC, DD, EV1, EV2, KB + 2); SWZFMA(B + 3, CC, DD, EV1, EV2, KB + 3); \
    SWZFMA(B + 4, CC, DD, EV1, EV2, KB + 4); SWZFMA(B + 5, CC, DD, EV1, EV2, KB + 5); \
    SWZFMA(B + 6, CC, DD, EV1, EV2, KB + 6); SWZFMA(B + 7, CC, DD, EV1, EV2, KB + 7)
    SWZ8(0,  c0, d0, e1a, e2a, 0);
    SWZ8(8,  c1, d1, e1a, e2a, 8);
    SWZ8(16, c2, d2, e1b, e2b, 0);
    SWZ8(24, c3, d3, e1b, e2b, 8);
#undef SWZ8
#undef SWZFMA
    float c = (c0 + c1) + (c2 + c3);
    float d = (d0 + d1) + (d2 + d3);
    return c + __shfl_xor(d, 32, 64);
}

#define LOADF(EV, MV, g) do {                                              \
    const int sb_ = 1 + (g) * GRP;                                         \
    _Pragma("unroll")                                                      \
    for (int k_ = 0; k_ < GRP; ++k_) {                                     \
        EV[k_] = embase[(size_t)(sb_ + k_) * BB * TT];                     \
        MV[k_] = mkbase[(sb_ + k_) * BB];                                  \
    } } while (0)

#define STEPSF(EV, MV, lastg) do {                                         \
    vf8 Em_;                                                               \
    _Pragma("unroll")                                                      \
    for (int k_ = 0; k_ < GRP; ++k_) Em_[k_] = __expf(EV[k_]);             \
    _Pragma("unroll")                                                      \
    for (int k_ = 0; k_ < GRP; ++k_) {                                     \
        float acc_ = swz_matvec(p, e1a, e1b, e2a, e2b);                    \
        float t_   = acc_ * Em_[k_];                                       \
        int   mk_  = MV[k_];                                               \
        if (k_ == GRP - 1) mk_ = (lastg) ? 0 : mk_;  /* virtual step 256 */\
        float sel_ = mk_ ? t_ : p;                                         \
        p = renorm(sel_, Lexp);                                            \
    } } while (0)

#define LOADB(EV, MV, g) do {                                              \
    const int sb_ = 511 - (g) * GRP;                                       \
    _Pragma("unroll")                                                      \
    for (int k_ = 0; k_ < GRP; ++k_) {                                     \
        EV[k_] = embase[(size_t)(sb_ - k_) * BB * TT];                     \
        MV[k_] = mkbase[(sb_ - k_) * BB];                                  \
    } } while (0)

#define STEPSB(EV, MV) do {                                                \
    vf8 Em_;                                                               \
    _Pragma("unroll")                                                      \
    for (int k_ = 0; k_ < GRP; ++k_) Em_[k_] = __expf(EV[k_]);             \
    _Pragma("unroll")                                                      \
    for (int k_ = 0; k_ < GRP; ++k_) {                                     \
        float u_   = q * Em_[k_];                                          \
        float acc_ = swz_matvec(u_, e1a, e1b, e2a, e2b);                   \
        float sel_ = MV[k_] ? acc_ : q;                                    \
        q = renorm(sel_, Lexp);                                            \
    } } while (0)

// blocks [0,B): forward chains; [B,2B): backward chains; [2B,3B): numerator.
// One wave per block; no barriers, no LDS arrays.
__global__ __launch_bounds__(64, 1) void crf_chains(
    const float* __restrict__ em,      // S,B,T
    const int*   __restrict__ tags,    // S,B
    const int*   __restrict__ mask,    // S,B
    const float* __restrict__ start_t, // T
    const float* __restrict__ end_t,   // T
    const float* __restrict__ trans,   // T,T
    float* __restrict__ alpha_mid,     // B,T
    float* __restrict__ beta_mid,      // B,T
    float* __restrict__ num_ws)        // B
{
    const int lane = threadIdx.x;
    const int bid  = blockIdx.x;
    const int hi   = lane & 32;        // which 32-half this lane is in

    if (bid < BB) {
        // ------------- forward: alpha_0 .. alpha_255 (exp domain) -------------
        const int b = bid;
        const float* embase = em + (size_t)b * TT + lane;
        const int*   mkbase = mask + b;

        // e1[i] = E[i+hi][lane], e2[i] = E[i+hi][lane^32]  (i = 0..31)
        vf16 e1a, e1b, e2a, e2b;
        #pragma unroll
        for (int i = 0; i < 16; ++i) {
            e1a[i] = __expf(trans[(i      + hi) * TT + lane]);
            e1b[i] = __expf(trans[(i + 16 + hi) * TT + lane]);
            e2a[i] = __expf(trans[(i      + hi) * TT + (lane ^ 32)]);
            e2b[i] = __expf(trans[(i + 16 + hi) * TT + (lane ^ 32)]);
        }

        float av    = start_t[lane] + embase[0];
        float Lbase = bl0(av);
        float p     = __expf(av - Lbase);
        int   Lexp  = 0;

        vf8 em0, em1;
        vi8 mk0, mk1;

        LOADF(em0, mk0, 0);
        LOADF(em1, mk1, 1);
        for (int gg = 0; gg < 32; gg += 2) {
            STEPSF(em0, mk0, false);
            LOADF(em0, mk0, gg + 2);
            STEPSF(em1, mk1, gg + 1 == 31);
            LOADF(em1, mk1, gg + 3);
        }
        double a = (double)Lbase + (double)Lexp * 0.6931471805599453 + (double)__logf(p);
        alpha_mid[(size_t)b * TT + lane] = (float)a;

    } else if (bid < 2 * BB) {
        // ------------- backward: beta_511 .. beta_255 (exp domain) -------------
        const int b = bid - BB;
        const float* embase = em + (size_t)b * TT + lane;
        const int*   mkbase = mask + b;

        // e1[j] = E[lane][j+hi], e2[j] = E[lane^32][j+hi]  (j = 0..31); trans is
        // 16 KB, L2-resident -> direct global reads are fine (once per block).
        vf16 e1a, e1b, e2a, e2b;
        #pragma unroll
        for (int j = 0; j < 16; ++j) {
            e1a[j] = __expf(trans[lane * TT        + (j      + hi)]);
            e1b[j] = __expf(trans[lane * TT        + (j + 16 + hi)]);
            e2a[j] = __expf(trans[(lane ^ 32) * TT + (j      + hi)]);
            e2b[j] = __expf(trans[(lane ^ 32) * TT + (j + 16 + hi)]);
        }

        float q    = __expf(end_t[lane]);
        int   Lexp = 0;

        vf8 em0, em1;
        vi8 mk0, mk1;

        LOADB(em0, mk0, 0);
        LOADB(em1, mk1, 1);
        for (int gg = 0; gg < 32; gg += 2) {
            STEPSB(em0, mk0);
            LOADB(em0, mk0, gg + 2);
            STEPSB(em1, mk1);
            LOADB(em1, mk1, gg + 3);
        }
        double bsum = (double)Lexp * 0.6931471805599453 + (double)__logf(q);
        beta_mid[(size_t)b * TT + lane] = (float)bsum;

    } else {
        // ---------------- numerator (tag-path score) ----------------
        const int b = bid - 2 * BB;
        float local = 0.f;
        int   mcnt  = 0;
        for (int s = lane; s < SS; s += 64) {
            int tag = tags[s * BB + b];
            int mk  = mask[s * BB + b];
            mcnt += mk;
            if (s == 0) {
                local += start_t[tag] + em[(size_t)b * TT + tag];
            } else if (mk) {
                int tp = tags[(s - 1) * BB + b];
                local += trans[tp * TT + tag] + em[(size_t)s * BB * TT + (size_t)b * TT + tag];
            }
        }
        #pragma unroll
        for (int d = 32; d > 0; d >>= 1) {
            local += __shfl_down(local, d, 64);
            mcnt  += __shfl_down(mcnt, d, 64);
        }
        if (lane == 0) {
            int last = tags[(mcnt - 1) * BB + b];
            num_ws[b] = local + end_t[last];
        }
    }
}

// per-batch denominator + llh: 64 blocks x 8 waves, one wave per batch.
__global__ __launch_bounds__(512) void crf_llh(
    const float* __restrict__ alpha_mid,
    const float* __restrict__ beta_mid,
    const float* __restrict__ num_ws,
    float* __restrict__ llh)
{
    const int lane = threadIdx.x & 63;
    const int b    = blockIdx.x * 8 + (threadIdx.x >> 6);
    float v = alpha_mid[(size_t)b * TT + lane] + beta_mid[(size_t)b * TT + lane];
    float mx = v;
    #pragma unroll
    for (int d = 32; d > 0; d >>= 1) mx = fmaxf(mx, __shfl_xor(mx, d, 64));
    float s = __expf(v - mx);
    #pragma unroll
    for (int d = 32; d > 0; d >>= 1) s += __shfl_xor(s, d, 64);
    if (lane == 0) llh[b] = num_ws[b] - (mx + __logf(s));
}

__global__ __launch_bounds__(512) void crf_mean(const float* __restrict__ llh,
                                               float* __restrict__ out)
{
    const int t = threadIdx.x;
    float v = llh[t];
    #pragma unroll
    for (int d = 32; d > 0; d >>= 1) v += __shfl_down(v, d, 64);
    __shared__ float red[8];
    if ((t & 63) == 0) red[t >> 6] = v;
    __syncthreads();
    if (t == 0) {
        float s = 0.f;
        #pragma unroll
        for (int w = 0; w < 8; ++w) s += red[w];
        out[0] = s / (float)BB;
    }
}

extern "C" void kernel_launch(void* const* d_in, const int* in_sizes, int n_in,
                              void* d_out, int out_size, void* d_ws, size_t ws_size,
                              hipStream_t stream) {
    const float* em    = (const float*)d_in[0];
    const int*   tags  = (const int*)d_in[1];
    const int*   mask  = (const int*)d_in[2];
    const float* st    = (const float*)d_in[3];
    const float* en    = (const float*)d_in[4];
    const float* tr    = (const float*)d_in[5];

    float* ws        = (float*)d_ws;
    float* alpha_mid = ws;
    float* beta_mid  = ws + (size_t)BB * TT;
    float* num_ws    = ws + (size_t)2 * BB * TT;
    float* llh       = ws + (size_t)2 * BB * TT + BB;

    crf_chains<<<3 * BB, 64, 0, stream>>>(em, tags, mask, st, en, tr,
                                          alpha_mid, beta_mid, num_ws);
    crf_llh<<<BB / 8, 512, 0, stream>>>(alpha_mid, beta_mid, num_ws, llh);
    crf_mean<<<1, 512, 0, stream>>>(llh, (float*)d_out);
}